// Round 5
// baseline (197.675 us; speedup 1.0000x reference)
//
#include <hip/hip_runtime.h>
#include <stdint.h>

#define C_LENX 2048
#define Q_LENX 512
#define BATCH  32
#define HDIM   256
#define BH     8192
#define CBLK   64
#define QBLK   32
#define NQT    16
#define TILE_BYTES 53248      // 16K qh(swz) + 16K ql(swz) + 20K qt(pitch40, sP holes)
#define OFF_QL 16384
#define OFF_QT 32768

typedef __attribute__((ext_vector_type(8))) short bf16x8;
typedef __attribute__((ext_vector_type(4))) float f32x4;

__device__ __forceinline__ unsigned short f2bf(float x) {
    unsigned int u = __float_as_uint(x);
    u += 0x7fffu + ((u >> 16) & 1u);        // round-to-nearest-even
    return (unsigned short)(u >> 16);
}
__device__ __forceinline__ float bf2f(unsigned short h) {
    return __uint_as_float(((unsigned int)h) << 16);
}

// async global->LDS, 16B per lane, wave-uniform LDS base + lane*16
__device__ __forceinline__ void stage16(const void* gsrc, void* ldst) {
    __builtin_amdgcn_global_load_lds(
        (const __attribute__((address_space(1))) unsigned int*)gsrc,
        (__attribute__((address_space(3))) unsigned int*)ldst, 16, 0, 0);
}

// ---------------- prep: fp32 Q -> fused per-tile blob (exact LDS image) ----------------
// layout per (b,t) tile, 53248B:
//   [0)      qh: row qr (512B), 16B-chunk swizzled: byte = qr*512 + ((h*2) ^ ((qr&7)<<4))
//   [16384)  ql: same mapping
//   [32768)  qt: Q^T hi, byte = h*80 + q*2  (bytes 64..79 of each row = sP holes, unwritten)
__global__ __launch_bounds__(256)
void q_prep(const float* __restrict__ question, unsigned char* __restrict__ blob)
{
    __shared__ unsigned short sHi[QBLK][264];
    const int tid = threadIdx.x;
    const int b  = blockIdx.x >> 4;
    const int t  = blockIdx.x & 15;
    const float* qbase = question + (size_t)(t * QBLK) * BH + b * HDIM;
    unsigned char* tb = blob + (size_t)(b * NQT + t) * TILE_BYTES;

    #pragma unroll
    for (int i = 0; i < 8; ++i) {
        int e  = tid + i * 256;          // float4 cell 0..2047
        int qr = e >> 6;                 // 0..31
        int h4 = (e & 63) << 2;          // 0..252
        float4 x = *reinterpret_cast<const float4*>(qbase + (size_t)qr * BH + h4);
        ushort4 hv, lv;
        hv.x = f2bf(x.x); hv.y = f2bf(x.y); hv.z = f2bf(x.z); hv.w = f2bf(x.w);
        lv.x = f2bf(x.x - bf2f(hv.x)); lv.y = f2bf(x.y - bf2f(hv.y));
        lv.z = f2bf(x.z - bf2f(hv.z)); lv.w = f2bf(x.w - bf2f(hv.w));
        *reinterpret_cast<ushort4*>(&sHi[qr][h4]) = hv;
        unsigned sw = ((unsigned)(h4 * 2)) ^ (((unsigned)qr & 7u) << 4);  // 8B-aligned preserved
        *reinterpret_cast<ushort4*>(tb + qr * 512 + sw) = hv;
        *reinterpret_cast<ushort4*>(tb + OFF_QL + qr * 512 + sw) = lv;
    }
    __syncthreads();
    #pragma unroll
    for (int i = 0; i < 8; ++i) {
        int e  = tid + i * 256;          // ushort4 cell of qt, 0..2047
        int h  = e >> 3;                 // 0..255
        int q4 = (e & 7) << 2;           // 0..28
        ushort4 v;
        v.x = sHi[q4 + 0][h]; v.y = sHi[q4 + 1][h];
        v.z = sHi[q4 + 2][h]; v.w = sHi[q4 + 3][h];
        *reinterpret_cast<ushort4*>(tb + OFF_QT + h * 80 + q4 * 2) = v;
    }
}

// ---------------- main fused attention ----------------
__global__ __launch_bounds__(256, 3)
void s2s_attn(const float* __restrict__ content,
              const unsigned char* __restrict__ blob,
              const int*   __restrict__ qmask,
              float*       __restrict__ out)
{
    __shared__ __attribute__((aligned(16))) unsigned char sBuf[TILE_BYTES];

    const int tid  = threadIdx.x;
    const int wid  = tid >> 6;
    const int lane = tid & 63;
    const int lr   = lane & 15;
    const int lg   = lane >> 4;

    // XCD-aware swizzle: each XCD owns 4 complete batches (blob L2 locality)
    const int lin = (blockIdx.x & 7) * 128 + (blockIdx.x >> 3);
    const int ct = lin & 31;
    const int b  = lin >> 5;
    const int c0 = ct * CBLK;

    // pack this thread's mask bits for all 16 tiles (rows lr and 16+lr)
    unsigned mb0 = 0, mb1 = 0;
    #pragma unroll
    for (int t = 0; t < NQT; ++t) {
        mb0 |= (qmask[b * Q_LENX + t * QBLK + lr]      ? 1u : 0u) << t;
        mb1 |= (qmask[b * Q_LENX + t * QBLK + 16 + lr] ? 1u : 0u) << t;
    }

    // prologue: stage tile 0 (52 segs of 1KB; 13 per wave)
    {
        const unsigned char* tb0 = blob + (size_t)(b * NQT) * TILE_BYTES;
        #pragma unroll
        for (int j = 0; j < 13; ++j) {
            int seg = wid * 13 + j;
            stage16(tb0 + seg * 1024 + lane * 16, sBuf + seg * 1024);
        }
    }

    // preload this wave's 16 content rows as hi/lo bf16 fragments
    bf16x8 chi[8], clo[8];
    {
        const float* cbase = content + (size_t)(c0 + wid*16 + lr) * BH + b*HDIM + lg*8;
        #pragma unroll
        for (int kc = 0; kc < 8; ++kc) {
            float4 x0 = *reinterpret_cast<const float4*>(cbase + kc*32);
            float4 x1 = *reinterpret_cast<const float4*>(cbase + kc*32 + 4);
            float xs[8] = {x0.x,x0.y,x0.z,x0.w,x1.x,x1.y,x1.z,x1.w};
            bf16x8 hi, lo;
            #pragma unroll
            for (int j = 0; j < 8; ++j) {
                unsigned short hb = f2bf(xs[j]);
                hi[j] = (short)hb;
                lo[j] = (short)f2bf(xs[j] - bf2f(hb));
            }
            chi[kc] = hi; clo[kc] = lo;
        }
    }

    f32x4 acc[16];
    #pragma unroll
    for (int n = 0; n < 16; ++n) { f32x4 z = {0.f,0.f,0.f,0.f}; acc[n] = z; }
    float m_run[4] = {-INFINITY,-INFINITY,-INFINITY,-INFINITY};
    float l_run[4] = {0.f,0.f,0.f,0.f};

    __syncthreads();   // drains vmcnt: tile 0 fully in LDS, visible to all

    for (int t = 0; t < NQT; ++t) {
        const unsigned char* tbn = blob + (size_t)(b * NQT + t + 1) * TILE_BYTES;

        // ---- QK^T (reads qh/ql, swizzled) ----
        const unsigned swz = ((unsigned)lr & 7u) << 4;   // (16+lr)&7 == lr&7
        f32x4 sacc0 = {0.f,0.f,0.f,0.f};
        f32x4 sacc1 = {0.f,0.f,0.f,0.f};
        __builtin_amdgcn_s_setprio(1);
        #pragma unroll
        for (int kc = 0; kc < 8; ++kc) {
            unsigned off = ((unsigned)(kc*64 + lg*16)) ^ swz;
            bf16x8 qh0 = *reinterpret_cast<const bf16x8*>(sBuf + lr*512 + off);
            bf16x8 ql0 = *reinterpret_cast<const bf16x8*>(sBuf + OFF_QL + lr*512 + off);
            bf16x8 qh1 = *reinterpret_cast<const bf16x8*>(sBuf + (16+lr)*512 + off);
            bf16x8 ql1 = *reinterpret_cast<const bf16x8*>(sBuf + OFF_QL + (16+lr)*512 + off);
            sacc0 = __builtin_amdgcn_mfma_f32_16x16x32_bf16(chi[kc], qh0, sacc0, 0, 0, 0);
            sacc0 = __builtin_amdgcn_mfma_f32_16x16x32_bf16(clo[kc], qh0, sacc0, 0, 0, 0);
            sacc0 = __builtin_amdgcn_mfma_f32_16x16x32_bf16(chi[kc], ql0, sacc0, 0, 0, 0);
            sacc1 = __builtin_amdgcn_mfma_f32_16x16x32_bf16(chi[kc], qh1, sacc1, 0, 0, 0);
            sacc1 = __builtin_amdgcn_mfma_f32_16x16x32_bf16(clo[kc], qh1, sacc1, 0, 0, 0);
            sacc1 = __builtin_amdgcn_mfma_f32_16x16x32_bf16(chi[kc], ql1, sacc1, 0, 0, 0);
        }
        __builtin_amdgcn_s_setprio(0);

        // ---- online softmax with defer-max (T13, THR=4) — numerics identical to R3/R4 ----
        const bool ok0 = (mb0 >> t) & 1u;
        const bool ok1 = (mb1 >> t) & 1u;
        float p0[4], p1[4], tmax[4];
        #pragma unroll
        for (int r = 0; r < 4; ++r) {
            float v0 = ok0 ? sacc0[r] : -INFINITY;
            float v1 = ok1 ? sacc1[r] : -INFINITY;
            p0[r] = v0; p1[r] = v1;
            tmax[r] = fmaxf(v0, v1);
        }
        #pragma unroll
        for (int off = 1; off < 16; off <<= 1) {
            #pragma unroll
            for (int r = 0; r < 4; ++r)
                tmax[r] = fmaxf(tmax[r], __shfl_xor(tmax[r], off, 64));
        }
        bool need = false;
        #pragma unroll
        for (int r = 0; r < 4; ++r) need |= (tmax[r] > m_run[r] + 4.0f);
        if (__ballot(need)) {           // wave-uniform rescale
            float scale[4];
            #pragma unroll
            for (int r = 0; r < 4; ++r) {
                float mnew = fmaxf(m_run[r], tmax[r]);
                if (mnew == -INFINITY) { scale[r] = 1.f; }
                else { scale[r] = __expf(m_run[r] - mnew); m_run[r] = mnew; }
                l_run[r] *= scale[r];
            }
            #pragma unroll
            for (int n = 0; n < 16; ++n) {
                #pragma unroll
                for (int r = 0; r < 4; ++r)
                    acc[n][r] *= scale[r];
            }
        }
        unsigned short pb0[4], pb1[4];
        float psum[4];
        #pragma unroll
        for (int r = 0; r < 4; ++r) {
            if (m_run[r] == -INFINITY) {
                pb0[r] = 0; pb1[r] = 0; psum[r] = 0.f;
            } else {
                float e0 = __expf(p0[r] - m_run[r]);   // bounded by e^4
                float e1 = __expf(p1[r] - m_run[r]);
                pb0[r] = f2bf(e0); pb1[r] = f2bf(e1);
                psum[r] = bf2f(pb0[r]) + bf2f(pb1[r]); // sum ROUNDED weights
            }
        }
        #pragma unroll
        for (int off = 1; off < 16; off <<= 1) {
            #pragma unroll
            for (int r = 0; r < 4; ++r)
                psum[r] += __shfl_xor(psum[r], off, 64);
        }
        #pragma unroll
        for (int r = 0; r < 4; ++r)
            l_run[r] += psum[r];

        // ---- P (bf16) into sQt's per-row 16B padding holes (wave-private) ----
        // hole chunk (wid, c, g) = qt row wid*64 + c*4 + g, bytes 64..79; holds P[c][g*8..g*8+7]
        #pragma unroll
        for (int r = 0; r < 4; ++r) {
            int c = lg * 4 + r;
            *reinterpret_cast<unsigned short*>(
                sBuf + OFF_QT + (wid*64 + c*4 + (lr>>3)) * 80 + 64 + (lr&7)*2) = pb0[r];
            *reinterpret_cast<unsigned short*>(
                sBuf + OFF_QT + (wid*64 + c*4 + 2 + (lr>>3)) * 80 + 64 + (lr&7)*2) = pb1[r];
        }
        bf16x8 pfrag = *reinterpret_cast<const bf16x8*>(
                sBuf + OFF_QT + (wid*64 + lr*4 + lg) * 80 + 64);

        __syncthreads();   // barrier A: all waves done with qh/ql(t) (+ own sP done)

        // prefetch qh/ql of t+1 under PV compute (segs 0..31, 8 per wave)
        if (t + 1 < NQT) {
            #pragma unroll
            for (int j = 0; j < 8; ++j) {
                int seg = wid * 8 + j;
                stage16(tbn + seg * 1024 + lane * 16, sBuf + seg * 1024);
            }
        }

        // ---- PV: acc[16 c x 256 h] += P(16x32) * Q(32x256), reads qt only ----
        __builtin_amdgcn_s_setprio(1);
        #pragma unroll
        for (int n = 0; n < 16; ++n) {
            bf16x8 vfrag = *reinterpret_cast<const bf16x8*>(
                    sBuf + OFF_QT + (n*16 + lr) * 80 + lg*16);
            acc[n] = __builtin_amdgcn_mfma_f32_16x16x32_bf16(pfrag, vfrag, acc[n], 0, 0, 0);
        }
        __builtin_amdgcn_s_setprio(0);

        __syncthreads();   // barrier B: all waves done with qt(t); qh/ql loads drained

        // prefetch qt of t+1 (segs 32..51, 5 per wave)
        if (t + 1 < NQT) {
            #pragma unroll
            for (int j = 0; j < 5; ++j) {
                int seg = 32 + wid * 5 + j;
                stage16(tbn + seg * 1024 + lane * 16, sBuf + seg * 1024);
            }
        }

        __syncthreads();   // barrier C: tile t+1 fully visible (auto vmcnt drain)
    }

    // ---- epilogue ----
    float rinv[4];
    #pragma unroll
    for (int r = 0; r < 4; ++r) rinv[r] = 1.f / l_run[r];
    float* obase = out + (size_t)(c0 + wid*16) * BH + b*HDIM;
    #pragma unroll
    for (int n = 0; n < 16; ++n) {
        #pragma unroll
        for (int r = 0; r < 4; ++r)
            obase[(size_t)(lg*4 + r) * BH + n*16 + lr] = acc[n][r] * rinv[r];
    }
}

extern "C" void kernel_launch(void* const* d_in, const int* in_sizes, int n_in,
                              void* d_out, int out_size, void* d_ws, size_t ws_size,
                              hipStream_t stream) {
    const float* content  = (const float*)d_in[0];
    const float* question = (const float*)d_in[1];
    const int*   mask     = (const int*)d_in[2];
    float*       out      = (float*)d_out;

    unsigned char* blob = (unsigned char*)d_ws;   // 512 tiles * 53248B = 26 MB

    q_prep<<<BATCH * NQT, 256, 0, stream>>>(question, blob);
    s2s_attn<<<C_LENX / CBLK * BATCH, 256, 0, stream>>>(content, blob, mask, out);
}